// Round 3
// baseline (525.415 us; speedup 1.0000x reference)
//
#include <hip/hip_runtime.h>
#include <hip/hip_fp16.h>
#include <cstdint>

#define D_IN   256
#define D_OUT  512
#define KK     64
#define BATCH  4096
#define EPSF   1e-12f

// ---------- helpers ----------------------------------------------------------

using half2v = _Float16 __attribute__((ext_vector_type(2)));

__device__ __forceinline__ float dot2(uint32_t a, uint32_t b, float c) {
#if defined(__has_builtin) && __has_builtin(__builtin_amdgcn_fdot2)
  return __builtin_amdgcn_fdot2(__builtin_bit_cast(half2v, a),
                                __builtin_bit_cast(half2v, b), c, false);
#else
  __half2 ah = __builtin_bit_cast(__half2, a);
  __half2 bh = __builtin_bit_cast(__half2, b);
  return c + __half2float(ah.x) * __half2float(bh.x)
           + __half2float(ah.y) * __half2float(bh.y);
#endif
}

__device__ __forceinline__ uint32_t packh2(float a, float b) {
  __half2 h = __floats2half2_rn(a, b);
  return __builtin_bit_cast(uint32_t, h);
}

// ---------- kernel 1: PCHIP slopes + packed fp16 quads ------------------------
// PK[i][k][o] = {C[o,i,k], C[o,i,k+1], d[o,i,k]*(h_k+EPS), d[o,i,k+1]*(h_k+EPS)}

__global__ __launch_bounds__(256)
void kan_pack(const float* __restrict__ coeffs,
              const float* __restrict__ knots,
              ushort4* __restrict__ pk) {
  __shared__ float s_kn[KK];
  __shared__ float s_h[KK];
  int tid = threadIdx.x;
  if (tid < KK) s_kn[tid] = knots[tid];
  __syncthreads();
  if (tid < KK - 1) s_h[tid] = s_kn[tid + 1] - s_kn[tid];
  __syncthreads();

  int o = blockIdx.x * 256 + tid;   // 0..511
  int i = blockIdx.y;               // 0..255
  const float* C = coeffs + ((size_t)o * D_IN + i) * KK;

  float c[KK];
#pragma unroll
  for (int k = 0; k < KK; k += 4) {
    float4 v = *(const float4*)(C + k);
    c[k] = v.x; c[k + 1] = v.y; c[k + 2] = v.z; c[k + 3] = v.w;
  }

  float d[KK];
  float h0 = s_h[0], h1 = s_h[1];
  float del0 = (c[1] - c[0]) / (h0 + EPSF);
  float del1 = (c[2] - c[1]) / (h1 + EPSF);
  {
    float di = ((2.f * h0 + h1) * del0 - h0 * del1) / (h0 + h1 + EPSF);
    di = (di * del0 <= 0.f) ? 0.f : di;
    di = (fabsf(di) > 3.f * fabsf(del0)) ? 3.f * del0 : di;
    d[0] = di;
  }
  float dp = del0, dn = del1;
#pragma unroll
  for (int k = 1; k <= KK - 2; ++k) {
    float hk = s_h[k], hkm = s_h[k - 1];
    float w1 = 2.f * hk + hkm;
    float w2 = hk + 2.f * hkm;
    float dint = (w1 + w2) / (w1 / (dp + EPSF) + w2 / (dn + EPSF) + EPSF);
    d[k] = (dp * dn > 0.f) ? dint : 0.f;
    if (k < KK - 2) {
      float nd = (c[k + 2] - c[k + 1]) / (s_h[k + 1] + EPSF);
      dp = dn; dn = nd;
    }
  }
  {
    float hN = s_h[KK - 2], hNm = s_h[KK - 3];
    float di = ((2.f * hN + hNm) * dn - hN * dp) / (hN + hNm + EPSF);
    di = (di * dn <= 0.f) ? 0.f : di;
    di = (fabsf(di) > 3.f * fabsf(dn)) ? 3.f * dn : di;
    d[KK - 1] = di;
  }

#pragma unroll
  for (int k = 0; k < KK - 1; ++k) {
    float hk = s_h[k] + EPSF;
    ushort4 q;
    q.x = __half_as_ushort(__float2half(c[k]));
    q.y = __half_as_ushort(__float2half(c[k + 1]));
    q.z = __half_as_ushort(__float2half(d[k] * hk));
    q.w = __half_as_ushort(__float2half(d[k + 1] * hk));
    pk[((size_t)i * KK + k) * D_OUT + o] = q;  // coalesced across o
  }
}

// ---------- kernel 2: per-(b,i) weights + row offsets --------------------------
// W[i*BATCH + b] = {w01=pack(wy0,wy1), w23=pack(wd0,wd1), rbyte=(i*64+k0)*4096, 0}

__global__ __launch_bounds__(512)
void kan_w(const float* __restrict__ x, uint4* __restrict__ W) {
  const int i = blockIdx.x;            // 0..255
  const float inv63 = 1.0f / 63.0f;
  for (int b = threadIdx.x; b < BATCH; b += 512) {
    float xv = x[(size_t)b * D_IN + i];   // scattered, but x is 4MB L2-resident
    float xc = fminf(fmaxf(xv, 0.f), 1.f);
    int k0 = (int)(xc * 63.0f);
    k0 = min(k0, KK - 2);
    float x0 = (float)k0 * inv63;
    if (xc < x0)                              { k0--; x0 -= inv63; }
    else if (k0 < KK - 2 && xc >= x0 + inv63) { k0++; x0 += inv63; }
    float t  = (xc - x0) * 63.0f;
    float t2 = t * t;
    float t3 = t2 * t;
    float wy0 = 2.f * t3 - 3.f * t2 + 1.f;   // h00
    float wy1 = 3.f * t2 - 2.f * t3;         // h01
    float wd0 = t3 - 2.f * t2 + t;           // h10 (h folded into PK)
    float wd1 = t3 - t2;                     // h11
    uint4 w;
    w.x = packh2(wy0, wy1);
    w.y = packh2(wd0, wd1);
    w.z = (uint32_t)(((i << 6) + k0) << 12); // PK row byte offset (4096 B rows)
    w.w = 0u;
    W[(size_t)i * BATCH + b] = w;            // coalesced across b
  }
}

// ---------- kernel 3: main gather + dot ----------------------------------------
// Block: 512 thr = 8 waves. Lane <-> o (64 consecutive, coalesced gathers).
// Wave handles 8 b. grid (8 otiles, 64 btiles) = 512 blocks = 2/CU.
// Inner loop is ONLY: 8 uniform W reads (scalar), 8 gathers, 16 v_dot2.

__global__ __launch_bounds__(512)
void kan_main(const uint4* __restrict__ Wt,
              const char* __restrict__ pkb,
              const float* __restrict__ bias,
              float* __restrict__ out) {
  const int tid  = threadIdx.x;
  const int lane = tid & 63;
  const int wave = tid >> 6;
  const int o    = blockIdx.x * 64 + lane;
  const int bw   = blockIdx.y * 64 + wave * 8;
  const int vo   = o * 8;                    // byte offset of lane's quad in a row

  float acc[8];
#pragma unroll
  for (int nb = 0; nb < 8; ++nb) acc[nb] = 0.f;

  for (int i = 0; i < D_IN; i += 2) {
    const uint4* WiA = Wt + (size_t)i * BATCH + bw;
    const uint4* WiB = WiA + BATCH;
    uint4 wA[8], wB[8];
#pragma unroll
    for (int nb = 0; nb < 8; ++nb) { wA[nb] = WiA[nb]; wB[nb] = WiB[nb]; }

    uint2 qA[8], qB[8];
#pragma unroll
    for (int nb = 0; nb < 8; ++nb)
      qA[nb] = *(const uint2*)(pkb + wA[nb].z + vo);
#pragma unroll
    for (int nb = 0; nb < 8; ++nb)
      qB[nb] = *(const uint2*)(pkb + wB[nb].z + vo);

#pragma unroll
    for (int nb = 0; nb < 8; ++nb) {
      acc[nb] = dot2(qA[nb].x, wA[nb].x, acc[nb]);
      acc[nb] = dot2(qA[nb].y, wA[nb].y, acc[nb]);
    }
#pragma unroll
    for (int nb = 0; nb < 8; ++nb) {
      acc[nb] = dot2(qB[nb].x, wB[nb].x, acc[nb]);
      acc[nb] = dot2(qB[nb].y, wB[nb].y, acc[nb]);
    }
  }

  float bv = bias[o];
#pragma unroll
  for (int nb = 0; nb < 8; ++nb)
    out[(size_t)(bw + nb) * D_OUT + o] = acc[nb] + bv;
}

// ---------- launch -------------------------------------------------------------

extern "C" void kernel_launch(void* const* d_in, const int* in_sizes, int n_in,
                              void* d_out, int out_size, void* d_ws, size_t ws_size,
                              hipStream_t stream) {
  const float* x      = (const float*)d_in[0];
  const float* coeffs = (const float*)d_in[1];
  const float* bias   = (const float*)d_in[2];
  const float* knots  = (const float*)d_in[3];
  float* out = (float*)d_out;

  const size_t pk_bytes = (size_t)D_IN * KK * D_OUT * 8;   // 64 MiB
  const size_t w_bytes  = (size_t)D_IN * BATCH * 16;       // 16 MiB
  if (ws_size < pk_bytes + w_bytes) return;  // loud failure (out stays poisoned)

  char* ws = (char*)d_ws;
  ushort4* pk = (ushort4*)ws;
  uint4*   W  = (uint4*)(ws + pk_bytes);

  kan_pack<<<dim3(D_OUT / 256, D_IN), 256, 0, stream>>>(coeffs, knots, pk);
  kan_w   <<<D_IN, 512, 0, stream>>>(x, W);
  kan_main<<<dim3(8, 64), 512, 0, stream>>>(W, (const char*)pk, bias, out);
}

// Round 4
// 306.671 us; speedup vs baseline: 1.7133x; 1.7133x over previous
//
#include <hip/hip_runtime.h>
#include <hip/hip_fp16.h>
#include <cstdint>

#define D_IN   256
#define D_OUT  512
#define KK     64
#define BATCH  4096
#define EPSF   1e-12f

// ---------- helpers ----------------------------------------------------------

using half2v = _Float16 __attribute__((ext_vector_type(2)));

__device__ __forceinline__ float dot2(uint32_t a, uint32_t b, float c) {
#if defined(__has_builtin) && __has_builtin(__builtin_amdgcn_fdot2)
  return __builtin_amdgcn_fdot2(__builtin_bit_cast(half2v, a),
                                __builtin_bit_cast(half2v, b), c, false);
#else
  __half2 ah = __builtin_bit_cast(__half2, a);
  __half2 bh = __builtin_bit_cast(__half2, b);
  return c + __half2float(ah.x) * __half2float(bh.x)
           + __half2float(ah.y) * __half2float(bh.y);
#endif
}

__device__ __forceinline__ uint32_t packh2(float a, float b) {
  __half2 h = __floats2half2_rn(a, b);
  return __builtin_bit_cast(uint32_t, h);
}

// ---------- kernel 1: PCHIP slopes + packed fp16 quads ------------------------
// PK[i][k][o] = {C[o,i,k], C[o,i,k+1], d[o,i,k]*(h_k+EPS), d[o,i,k+1]*(h_k+EPS)}

__global__ __launch_bounds__(256)
void kan_pack(const float* __restrict__ coeffs,
              const float* __restrict__ knots,
              ushort4* __restrict__ pk) {
  __shared__ float s_kn[KK];
  __shared__ float s_h[KK];
  int tid = threadIdx.x;
  if (tid < KK) s_kn[tid] = knots[tid];
  __syncthreads();
  if (tid < KK - 1) s_h[tid] = s_kn[tid + 1] - s_kn[tid];
  __syncthreads();

  int o = blockIdx.x * 256 + tid;   // 0..511
  int i = blockIdx.y;               // 0..255
  const float* C = coeffs + ((size_t)o * D_IN + i) * KK;

  float c[KK];
#pragma unroll
  for (int k = 0; k < KK; k += 4) {
    float4 v = *(const float4*)(C + k);
    c[k] = v.x; c[k + 1] = v.y; c[k + 2] = v.z; c[k + 3] = v.w;
  }

  float d[KK];
  float h0 = s_h[0], h1 = s_h[1];
  float del0 = (c[1] - c[0]) / (h0 + EPSF);
  float del1 = (c[2] - c[1]) / (h1 + EPSF);
  {
    float di = ((2.f * h0 + h1) * del0 - h0 * del1) / (h0 + h1 + EPSF);
    di = (di * del0 <= 0.f) ? 0.f : di;
    di = (fabsf(di) > 3.f * fabsf(del0)) ? 3.f * del0 : di;
    d[0] = di;
  }
  float dp = del0, dn = del1;
#pragma unroll
  for (int k = 1; k <= KK - 2; ++k) {
    float hk = s_h[k], hkm = s_h[k - 1];
    float w1 = 2.f * hk + hkm;
    float w2 = hk + 2.f * hkm;
    float dint = (w1 + w2) / (w1 / (dp + EPSF) + w2 / (dn + EPSF) + EPSF);
    d[k] = (dp * dn > 0.f) ? dint : 0.f;
    if (k < KK - 2) {
      float nd = (c[k + 2] - c[k + 1]) / (s_h[k + 1] + EPSF);
      dp = dn; dn = nd;
    }
  }
  {
    float hN = s_h[KK - 2], hNm = s_h[KK - 3];
    float di = ((2.f * hN + hNm) * dn - hN * dp) / (hN + hNm + EPSF);
    di = (di * dn <= 0.f) ? 0.f : di;
    di = (fabsf(di) > 3.f * fabsf(dn)) ? 3.f * dn : di;
    d[KK - 1] = di;
  }

#pragma unroll
  for (int k = 0; k < KK - 1; ++k) {
    float hk = s_h[k] + EPSF;
    ushort4 q;
    q.x = __half_as_ushort(__float2half(c[k]));
    q.y = __half_as_ushort(__float2half(c[k + 1]));
    q.z = __half_as_ushort(__float2half(d[k] * hk));
    q.w = __half_as_ushort(__float2half(d[k + 1] * hk));
    pk[((size_t)i * KK + k) * D_OUT + o] = q;  // coalesced across o
  }
}

// ---------- kernel 2: per-(b,i) weights + row offsets --------------------------
// W[i*BATCH + b] = {w01, w23, rbyte=(i*64+k0)*4096, 0}

__global__ __launch_bounds__(512)
void kan_w(const float* __restrict__ x, uint4* __restrict__ W) {
  const int i = blockIdx.x;            // 0..255
  const float inv63 = 1.0f / 63.0f;
  for (int b = threadIdx.x; b < BATCH; b += 512) {
    float xv = x[(size_t)b * D_IN + i];   // scattered; x is 4MB, L2/L3-resident
    float xc = fminf(fmaxf(xv, 0.f), 1.f);
    int k0 = (int)(xc * 63.0f);
    k0 = min(k0, KK - 2);
    float x0 = (float)k0 * inv63;
    if (xc < x0)                              { k0--; x0 -= inv63; }
    else if (k0 < KK - 2 && xc >= x0 + inv63) { k0++; x0 += inv63; }
    float t  = (xc - x0) * 63.0f;
    float t2 = t * t;
    float t3 = t2 * t;
    float wy0 = 2.f * t3 - 3.f * t2 + 1.f;   // h00
    float wy1 = 3.f * t2 - 2.f * t3;         // h01
    float wd0 = t3 - 2.f * t2 + t;           // h10 (h folded into PK)
    float wd1 = t3 - t2;                     // h11
    uint4 w;
    w.x = packh2(wy0, wy1);
    w.y = packh2(wd0, wd1);
    w.z = (uint32_t)(((i << 6) + k0) << 12); // PK row byte offset (4096 B rows)
    w.w = 0u;
    W[(size_t)i * BATCH + b] = w;            // coalesced across b
  }
}

// ---------- kernel 3: main gather + dot ----------------------------------------
// Block: 512 thr = 8 waves; wave w covers o = w*64+lane -> ALL 512 o per block.
// Block owns 8 batch rows; W read ONCE per (b,i) (same-line broadcast in-block).
// grid = 512 blocks (2/CU). W prefetched one i ahead to break load->gather chain.

__global__ __launch_bounds__(512, 4)
void kan_main(const uint4* __restrict__ Wt,
              const char* __restrict__ pkb,
              const float* __restrict__ bias,
              float* __restrict__ out) {
  const int tid  = threadIdx.x;
  const int o    = tid;                      // wave w -> o in [w*64, w*64+64)
  const int bw   = blockIdx.x * 8;           // this block's 8 batch rows
  const int vo   = o * 8;                    // lane's byte offset within a PK row

  float acc[8];
#pragma unroll
  for (int nb = 0; nb < 8; ++nb) acc[nb] = 0.f;

  uint4 w[8], wn[8];
#pragma unroll
  for (int nb = 0; nb < 8; ++nb) w[nb] = Wt[bw + nb];

  for (int i = 0; i < D_IN; ++i) {
    const size_t nxt = (size_t)min(i + 1, D_IN - 1) * BATCH + bw;
#pragma unroll
    for (int nb = 0; nb < 8; ++nb) wn[nb] = Wt[nxt + nb];   // prefetch i+1

    uint2 q[8];
#pragma unroll
    for (int nb = 0; nb < 8; ++nb)
      q[nb] = *(const uint2*)(pkb + w[nb].z + vo);          // 512B/wave, 1 row

#pragma unroll
    for (int nb = 0; nb < 8; ++nb) {
      acc[nb] = dot2(q[nb].x, w[nb].x, acc[nb]);            // wy0*C0 + wy1*C1
      acc[nb] = dot2(q[nb].y, w[nb].y, acc[nb]);            // wd0*D0h + wd1*D1h
    }
#pragma unroll
    for (int nb = 0; nb < 8; ++nb) w[nb] = wn[nb];
  }

  float bv = bias[o];
#pragma unroll
  for (int nb = 0; nb < 8; ++nb)
    out[(size_t)(bw + nb) * D_OUT + o] = acc[nb] + bv;
}

// ---------- launch -------------------------------------------------------------

extern "C" void kernel_launch(void* const* d_in, const int* in_sizes, int n_in,
                              void* d_out, int out_size, void* d_ws, size_t ws_size,
                              hipStream_t stream) {
  const float* x      = (const float*)d_in[0];
  const float* coeffs = (const float*)d_in[1];
  const float* bias   = (const float*)d_in[2];
  const float* knots  = (const float*)d_in[3];
  float* out = (float*)d_out;

  const size_t pk_bytes = (size_t)D_IN * KK * D_OUT * 8;   // 64 MiB
  const size_t w_bytes  = (size_t)D_IN * BATCH * 16;       // 16 MiB
  if (ws_size < pk_bytes + w_bytes) return;  // loud failure (out stays poisoned)

  char* ws = (char*)d_ws;
  ushort4* pk = (ushort4*)ws;
  uint4*   W  = (uint4*)(ws + pk_bytes);

  kan_pack<<<dim3(D_OUT / 256, D_IN), 256, 0, stream>>>(coeffs, knots, pk);
  kan_w   <<<D_IN, 512, 0, stream>>>(x, W);
  kan_main<<<dim3(BATCH / 8), 512, 0, stream>>>(W, (const char*)pk, bias, out);
}